// Round 7
// baseline (974.076 us; speedup 1.0000x reference)
//
#include <hip/hip_runtime.h>
#include <stdint.h>

// x: (32, 256, 58, 58) f32 binary {0,1};  w: (256, 256, 3, 3) f32
// out: (32, 256, 56, 56) f32 = alpha[o]*(2S - 2304), S = XNOR matches.
// Identity: conv(1-x,1-bw) = 2304 - Sx_win - Sbw[o] + conv(x,bw)  =>
//   out = (4a[o])*conv(x,bw) + a[o]*(2304 - 2*Sbw[o]) - (2a[o])*Sx_win
// conv(x,bw) runs on the i8 matrix pipe (R3-R5: VALU xor/bcnt wall ~130us;
// MfmaUtil was 0; i8 MFMA floor for 118.4e9 ops is ~27us).
// R6 bug: xq region was sized 107,584*256 instead of NPIX*256 = 107,648*256,
// so wq overlapped xq's last 64 pixels -> localized full-scale errors. Fixed.

#define BATCH 32
#define C_IN 256
#define OCH 256
#define HIN 58
#define WIN2 58
#define HOUT 56
#define WOUT 56
#define TAPS 9
#define HWIN (HIN * WIN2)    // 3364
#define HWOUT (HOUT * WOUT)  // 3136
#define NPIX (BATCH * HWIN)  // 107648 input pixels
#define NPOS (BATCH * HWOUT) // 100352 output positions

typedef int v4i  __attribute__((ext_vector_type(4)));
typedef int v16i __attribute__((ext_vector_type(16)));

// ---------------------------------------------------------------------------
// Kernel 1: x -> channel-last i8 [b][y][x][256] + per-pixel channel-sum ps.
// ---------------------------------------------------------------------------
__global__ __launch_bounds__(256) void pack_xi8_kernel(
    const float* __restrict__ x, uint8_t* __restrict__ xq, int* __restrict__ ps)
{
    int t = blockIdx.x * 256 + threadIdx.x;
    if (t >= NPIX) return;
    int b = t / HWIN;
    int r = t - b * HWIN;
    const float* xb = x + (size_t)b * C_IN * HWIN + r;
    int sum = 0;
    #pragma unroll 2
    for (int cg = 0; cg < 16; ++cg) {          // 16 channels -> one 16B store
        uint32_t wd[4];
        #pragma unroll
        for (int k = 0; k < 4; ++k) {
            uint32_t v = 0;
            #pragma unroll
            for (int j = 0; j < 4; ++j) {
                float f = xb[(size_t)(cg * 16 + k * 4 + j) * HWIN];
                uint32_t bit = f > 0.5f ? 1u : 0u;
                v |= bit << (8 * j);
                sum += (int)bit;
            }
            wd[k] = v;
        }
        *(uint4*)(xq + (size_t)t * 256 + cg * 16) =
            make_uint4(wd[0], wd[1], wd[2], wd[3]);
    }
    ps[t] = sum;
}

// ---------------------------------------------------------------------------
// Kernel 2: 3x3 box-sum of per-pixel sums -> Sx_win per output position.
// ---------------------------------------------------------------------------
__global__ __launch_bounds__(256) void boxsum_kernel(
    const int* __restrict__ ps, int* __restrict__ bs)
{
    int t = blockIdx.x * 256 + threadIdx.x;    // 392 blocks exactly
    int b = t / HWOUT;
    int s = t - b * HWOUT;
    int oy = s / WOUT;
    int ox = s - oy * WOUT;
    const int* p = ps + (b * HIN + oy) * WIN2 + ox;
    int acc = 0;
    #pragma unroll
    for (int dy = 0; dy < 3; ++dy)
        #pragma unroll
        for (int dx = 0; dx < 3; ++dx)
            acc += p[dy * WIN2 + dx];
    bs[t] = acc;
}

// ---------------------------------------------------------------------------
// Kernel 3: weights -> i8 {0,1} in [tap][o][c] + per-o scale triple
//   scales[o] = (4a, a*(2304 - 2*Sbw), 2a, 0)
// ---------------------------------------------------------------------------
__global__ __launch_bounds__(256) void pack_w_kernel(
    const float* __restrict__ wt, uint8_t* __restrict__ wq,
    float4* __restrict__ scales)
{
    int o = blockIdx.x;
    int c = threadIdx.x;
    const float* wb = wt + ((size_t)o * C_IN + c) * TAPS;
    float s = 0.f;
    int cnt = 0;
    #pragma unroll
    for (int t = 0; t < TAPS; ++t) {
        float v = wb[t];
        s += fabsf(v);
        uint8_t bitv = (v >= 0.0f) ? 1 : 0;
        cnt += bitv;
        wq[((size_t)t * OCH + o) * C_IN + c] = bitv;
    }
    __shared__ float rs[256];
    __shared__ int   rc[256];
    rs[c] = s;
    rc[c] = cnt;
    __syncthreads();
    for (int off = 128; off > 0; off >>= 1) {
        if (c < off) { rs[c] += rs[c + off]; rc[c] += rc[c + off]; }
        __syncthreads();
    }
    if (c == 0) {
        float alpha = rs[0] / (float)(C_IN * HWIN);  // n = C*H*W per reference
        float4 sc;
        sc.x = 4.0f * alpha;
        sc.y = alpha * (float)(C_IN * TAPS - 2 * rc[0]);
        sc.z = 2.0f * alpha;
        sc.w = 0.0f;
        scales[o] = sc;
    }
}

// ---------------------------------------------------------------------------
// Kernel 4: main i8 MFMA conv as 9 shifted GEMMs (K = 8 c-chunks x 9 taps).
// A = weights (M = o), B = x (N = positions) so C/D cols = positions ->
// coalesced stores. Both operands loaded per-lane dwordx4 DIRECT from
// global (no LDS): B working set ~10KB/block (L1), weights 576KB (L2).
// Wave tile: 64o x 128pos = acc[2][4] of v16i.  Block: 4 waves.
// Note: A/B per-lane k-map errors cancel as long as A and B use the same
// bijection (slot-to-slot pairing is permutation-invariant); C/D layout is
// the HW-verified shape-determined mapping.
// ---------------------------------------------------------------------------
__global__ __launch_bounds__(256, 3) void xnor_mfma_kernel(
    const uint8_t* __restrict__ xq, const uint8_t* __restrict__ wq,
    const float4* __restrict__ scales, const int* __restrict__ bs,
    float* __restrict__ out)
{
    const int lane  = threadIdx.x & 63;
    const int wv    = threadIdx.x >> 6;
    const int khalf = lane >> 5;
    const int mn    = lane & 31;

    const int osub   = blockIdx.y * 128 + (wv & 1) * 64;
    const int possub = blockIdx.x * 256 + (wv >> 1) * 128;

    // A (weights) per-lane base: row o = osub + mn (mt=1 adds 32*256=8192)
    const uint32_t abase = (uint32_t)(osub + mn) * C_IN + khalf * 16;

    // B (x) per-lane pixel bases for the 4 position sub-tiles
    uint32_t pb[4];
    #pragma unroll
    for (int f = 0; f < 4; ++f) {
        int pos = possub + f * 32 + mn;
        int b = pos / HWOUT;
        int s = pos - b * HWOUT;
        int oy = s / WOUT;
        int ox = s - oy * WOUT;
        pb[f] = (uint32_t)((b * HIN + oy) * WIN2 + ox) * C_IN + khalf * 16;
    }

    v16i acc[2][4];
    #pragma unroll
    for (int mt = 0; mt < 2; ++mt)
        #pragma unroll
        for (int nt = 0; nt < 4; ++nt)
            #pragma unroll
            for (int e = 0; e < 16; ++e)
                acc[mt][nt][e] = 0;

    const int TAPOFF[TAPS] = {0, 1, 2, 58, 59, 60, 116, 117, 118}; // dy*58+dx

    #pragma unroll 1
    for (int c0 = 0; c0 < C_IN; c0 += 32) {
        #pragma unroll
        for (int tap = 0; tap < TAPS; ++tap) {
            uint32_t aoff = (uint32_t)tap * (OCH * C_IN) + c0;
            uint32_t boff = (uint32_t)TAPOFF[tap] * C_IN + c0;
            v4i a0 = *(const v4i*)(wq + abase + aoff);
            v4i a1 = *(const v4i*)(wq + abase + aoff + 32 * C_IN);
            v4i b0 = *(const v4i*)(xq + pb[0] + boff);
            v4i b1 = *(const v4i*)(xq + pb[1] + boff);
            v4i b2 = *(const v4i*)(xq + pb[2] + boff);
            v4i b3 = *(const v4i*)(xq + pb[3] + boff);
            acc[0][0] = __builtin_amdgcn_mfma_i32_32x32x32_i8(a0, b0, acc[0][0], 0, 0, 0);
            acc[0][1] = __builtin_amdgcn_mfma_i32_32x32x32_i8(a0, b1, acc[0][1], 0, 0, 0);
            acc[0][2] = __builtin_amdgcn_mfma_i32_32x32x32_i8(a0, b2, acc[0][2], 0, 0, 0);
            acc[0][3] = __builtin_amdgcn_mfma_i32_32x32x32_i8(a0, b3, acc[0][3], 0, 0, 0);
            acc[1][0] = __builtin_amdgcn_mfma_i32_32x32x32_i8(a1, b0, acc[1][0], 0, 0, 0);
            acc[1][1] = __builtin_amdgcn_mfma_i32_32x32x32_i8(a1, b1, acc[1][1], 0, 0, 0);
            acc[1][2] = __builtin_amdgcn_mfma_i32_32x32x32_i8(a1, b2, acc[1][2], 0, 0, 0);
            acc[1][3] = __builtin_amdgcn_mfma_i32_32x32x32_i8(a1, b3, acc[1][3], 0, 0, 0);
        }
    }

    // Epilogue. C/D layout (32x32): col = lane&31 (=position),
    // row = (reg&3) + 8*(reg>>2) + 4*khalf (=o offset).
    #pragma unroll
    for (int f = 0; f < 4; ++f) {
        int pos = possub + f * 32 + mn;
        int b = pos / HWOUT;
        int s = pos - b * HWOUT;
        float bsv = (float)bs[pos];
        size_t obase = (size_t)b * (OCH * HWOUT) + s;
        #pragma unroll
        for (int mt = 0; mt < 2; ++mt) {
            #pragma unroll
            for (int rg = 0; rg < 4; ++rg) {
                #pragma unroll
                for (int j = 0; j < 4; ++j) {
                    int o = osub + mt * 32 + rg * 8 + j + 4 * khalf;
                    float4 sc = scales[o];
                    float v = (float)acc[mt][f][rg * 4 + j];
                    out[obase + (size_t)o * HWOUT] =
                        fmaf(sc.x, v, fmaf(-sc.z, bsv, sc.y));
                }
            }
        }
    }
}

// ---------------------------------------------------------------------------
extern "C" void kernel_launch(void* const* d_in, const int* in_sizes, int n_in,
                              void* d_out, int out_size, void* d_ws, size_t ws_size,
                              hipStream_t stream)
{
    const float* x  = (const float*)d_in[0];
    const float* wt = (const float*)d_in[1];
    float* out = (float*)d_out;

    // Workspace (~27.7 MB), NO overlaps (R6 fix):
    //   xq     [0,          27557888)   = NPIX*256
    //   wq     [27557888,   28147712)   = 9*256*256
    //   scales [28147712,   28151808)   = 256*16
    //   ps     [28151808,   28582400)   = NPIX*4
    //   bs     [28582400,   28983808)   = NPOS*4
    char* ws = (char*)d_ws;
    uint8_t* xq     = (uint8_t*)ws;
    uint8_t* wq     = (uint8_t*)(ws + 27557888);
    float4*  scales = (float4*)(ws + 28147712);
    int*     ps     = (int*)(ws + 28151808);
    int*     bs     = (int*)(ws + 28582400);

    // 1) x -> i8 channel-last + pixel sums (107,648 px -> 421 blocks)
    pack_xi8_kernel<<<dim3(421), dim3(256), 0, stream>>>(x, xq, ps);

    // 2) weights -> i8 [tap][o][c] + scale triples
    pack_w_kernel<<<dim3(OCH), dim3(256), 0, stream>>>(wt, wq, scales);

    // 3) 3x3 box-sum of pixel sums (100,352 -> 392 blocks)
    boxsum_kernel<<<dim3(392), dim3(256), 0, stream>>>(ps, bs);

    // 4) main MFMA conv: 392 pos-blocks x 2 o-blocks, 4 waves each
    xnor_mfma_kernel<<<dim3(392, 2), dim3(256), 0, stream>>>(xq, wq, scales, bs, out);
}

// Round 8
// 522.309 us; speedup vs baseline: 1.8649x; 1.8649x over previous
//
#include <hip/hip_runtime.h>
#include <stdint.h>

// x: (32, 256, 58, 58) f32 binary {0,1};  w: (256, 256, 3, 3) f32
// out: (32, 256, 56, 56) f32 = alpha[o]*(2S - 2304), S = XNOR matches.
// Identity: conv(1-x,1-bw) = 2304 - Sx_win - Sbw[o] + conv(x,bw)  =>
//   out = (4a[o])*conv(x,bw) + a[o]*(2304 - 2*Sbw[o]) - (2a[o])*Sx_win
// conv(x,bw) on the i8 matrix pipe (R3-R5: VALU xor/bcnt wall ~130us).
// R7 lesson: acc[2][4] v16i = 128 acc regs + ~85 arch > 170-reg cap from
// launch_bounds(256,3) -> accumulator spill, 1.5GB scratch writes, 715us.
// Fix: launch_bounds(256,2) -> 256-reg unified budget, 2 waves/SIMD.

#define BATCH 32
#define C_IN 256
#define OCH 256
#define HIN 58
#define WIN2 58
#define HOUT 56
#define WOUT 56
#define TAPS 9
#define HWIN (HIN * WIN2)    // 3364
#define HWOUT (HOUT * WOUT)  // 3136
#define NPIX (BATCH * HWIN)  // 107648 input pixels
#define NPOS (BATCH * HWOUT) // 100352 output positions

typedef int v4i  __attribute__((ext_vector_type(4)));
typedef int v16i __attribute__((ext_vector_type(16)));

// ---------------------------------------------------------------------------
// Kernel 1: x -> channel-last i8 [b][y][x][256] + per-pixel channel-sum ps.
// ---------------------------------------------------------------------------
__global__ __launch_bounds__(256) void pack_xi8_kernel(
    const float* __restrict__ x, uint8_t* __restrict__ xq, int* __restrict__ ps)
{
    int t = blockIdx.x * 256 + threadIdx.x;
    if (t >= NPIX) return;
    int b = t / HWIN;
    int r = t - b * HWIN;
    const float* xb = x + (size_t)b * C_IN * HWIN + r;
    int sum = 0;
    #pragma unroll 2
    for (int cg = 0; cg < 16; ++cg) {          // 16 channels -> one 16B store
        uint32_t wd[4];
        #pragma unroll
        for (int k = 0; k < 4; ++k) {
            uint32_t v = 0;
            #pragma unroll
            for (int j = 0; j < 4; ++j) {
                float f = xb[(size_t)(cg * 16 + k * 4 + j) * HWIN];
                uint32_t bit = f > 0.5f ? 1u : 0u;
                v |= bit << (8 * j);
                sum += (int)bit;
            }
            wd[k] = v;
        }
        *(uint4*)(xq + (size_t)t * 256 + cg * 16) =
            make_uint4(wd[0], wd[1], wd[2], wd[3]);
    }
    ps[t] = sum;
}

// ---------------------------------------------------------------------------
// Kernel 2: 3x3 box-sum of per-pixel sums -> Sx_win per output position.
// ---------------------------------------------------------------------------
__global__ __launch_bounds__(256) void boxsum_kernel(
    const int* __restrict__ ps, int* __restrict__ bs)
{
    int t = blockIdx.x * 256 + threadIdx.x;    // 392 blocks exactly
    int b = t / HWOUT;
    int s = t - b * HWOUT;
    int oy = s / WOUT;
    int ox = s - oy * WOUT;
    const int* p = ps + (b * HIN + oy) * WIN2 + ox;
    int acc = 0;
    #pragma unroll
    for (int dy = 0; dy < 3; ++dy)
        #pragma unroll
        for (int dx = 0; dx < 3; ++dx)
            acc += p[dy * WIN2 + dx];
    bs[t] = acc;
}

// ---------------------------------------------------------------------------
// Kernel 3: weights -> i8 {0,1} in [tap][o][c] + per-o scale triple
//   scales[o] = (4a, a*(2304 - 2*Sbw), 2a, 0)
// ---------------------------------------------------------------------------
__global__ __launch_bounds__(256) void pack_w_kernel(
    const float* __restrict__ wt, uint8_t* __restrict__ wq,
    float4* __restrict__ scales)
{
    int o = blockIdx.x;
    int c = threadIdx.x;
    const float* wb = wt + ((size_t)o * C_IN + c) * TAPS;
    float s = 0.f;
    int cnt = 0;
    #pragma unroll
    for (int t = 0; t < TAPS; ++t) {
        float v = wb[t];
        s += fabsf(v);
        uint8_t bitv = (v >= 0.0f) ? 1 : 0;
        cnt += bitv;
        wq[((size_t)t * OCH + o) * C_IN + c] = bitv;
    }
    __shared__ float rs[256];
    __shared__ int   rc[256];
    rs[c] = s;
    rc[c] = cnt;
    __syncthreads();
    for (int off = 128; off > 0; off >>= 1) {
        if (c < off) { rs[c] += rs[c + off]; rc[c] += rc[c + off]; }
        __syncthreads();
    }
    if (c == 0) {
        float alpha = rs[0] / (float)(C_IN * HWIN);  // n = C*H*W per reference
        float4 sc;
        sc.x = 4.0f * alpha;
        sc.y = alpha * (float)(C_IN * TAPS - 2 * rc[0]);
        sc.z = 2.0f * alpha;
        sc.w = 0.0f;
        scales[o] = sc;
    }
}

// ---------------------------------------------------------------------------
// Kernel 4: main i8 MFMA conv as 9 shifted GEMMs (K = 8 c-chunks x 9 taps).
// A = weights (M = o), B = x (N = positions) -> C/D cols = positions ->
// coalesced stores. Operands per-lane dwordx4 DIRECT from global (no LDS):
// B working set ~104KB/block (L2), weights 576KB (L2/L3).
// Wave tile: 64o x 128pos = acc[2][4] of v16i (128 acc regs). 4 waves/block.
// launch_bounds(256,2): 256-reg unified budget fits 128 acc + ~85 arch.
// ---------------------------------------------------------------------------
__global__ __launch_bounds__(256, 2) void xnor_mfma_kernel(
    const uint8_t* __restrict__ xq, const uint8_t* __restrict__ wq,
    const float4* __restrict__ scales, const int* __restrict__ bs,
    float* __restrict__ out)
{
    const int lane  = threadIdx.x & 63;
    const int wv    = threadIdx.x >> 6;
    const int khalf = lane >> 5;
    const int mn    = lane & 31;

    const int osub   = blockIdx.y * 128 + (wv & 1) * 64;
    const int possub = blockIdx.x * 256 + (wv >> 1) * 128;

    // A (weights) per-lane base: row o = osub + mn (mt=1 adds 32*256=8192)
    const uint32_t abase = (uint32_t)(osub + mn) * C_IN + khalf * 16;

    // B (x) per-lane pixel bases for the 4 position sub-tiles
    uint32_t pb[4];
    #pragma unroll
    for (int f = 0; f < 4; ++f) {
        int pos = possub + f * 32 + mn;
        int b = pos / HWOUT;
        int s = pos - b * HWOUT;
        int oy = s / WOUT;
        int ox = s - oy * WOUT;
        pb[f] = (uint32_t)((b * HIN + oy) * WIN2 + ox) * C_IN + khalf * 16;
    }

    v16i acc[2][4];
    #pragma unroll
    for (int mt = 0; mt < 2; ++mt)
        #pragma unroll
        for (int nt = 0; nt < 4; ++nt)
            #pragma unroll
            for (int e = 0; e < 16; ++e)
                acc[mt][nt][e] = 0;

    const int TAPOFF[TAPS] = {0, 1, 2, 58, 59, 60, 116, 117, 118}; // dy*58+dx

    #pragma unroll 1
    for (int c0 = 0; c0 < C_IN; c0 += 32) {
        #pragma unroll
        for (int tap = 0; tap < TAPS; ++tap) {
            uint32_t aoff = (uint32_t)tap * (OCH * C_IN) + c0;
            uint32_t boff = (uint32_t)TAPOFF[tap] * C_IN + c0;
            v4i a0 = *(const v4i*)(wq + abase + aoff);
            v4i a1 = *(const v4i*)(wq + abase + aoff + 32 * C_IN);
            v4i b0 = *(const v4i*)(xq + pb[0] + boff);
            v4i b1 = *(const v4i*)(xq + pb[1] + boff);
            v4i b2 = *(const v4i*)(xq + pb[2] + boff);
            v4i b3 = *(const v4i*)(xq + pb[3] + boff);
            acc[0][0] = __builtin_amdgcn_mfma_i32_32x32x32_i8(a0, b0, acc[0][0], 0, 0, 0);
            acc[0][1] = __builtin_amdgcn_mfma_i32_32x32x32_i8(a0, b1, acc[0][1], 0, 0, 0);
            acc[0][2] = __builtin_amdgcn_mfma_i32_32x32x32_i8(a0, b2, acc[0][2], 0, 0, 0);
            acc[0][3] = __builtin_amdgcn_mfma_i32_32x32x32_i8(a0, b3, acc[0][3], 0, 0, 0);
            acc[1][0] = __builtin_amdgcn_mfma_i32_32x32x32_i8(a1, b0, acc[1][0], 0, 0, 0);
            acc[1][1] = __builtin_amdgcn_mfma_i32_32x32x32_i8(a1, b1, acc[1][1], 0, 0, 0);
            acc[1][2] = __builtin_amdgcn_mfma_i32_32x32x32_i8(a1, b2, acc[1][2], 0, 0, 0);
            acc[1][3] = __builtin_amdgcn_mfma_i32_32x32x32_i8(a1, b3, acc[1][3], 0, 0, 0);
        }
    }

    // Epilogue. C/D layout (32x32): col = lane&31 (=position),
    // row = (reg&3) + 8*(reg>>2) + 4*khalf (=o offset).
    #pragma unroll
    for (int f = 0; f < 4; ++f) {
        int pos = possub + f * 32 + mn;
        int b = pos / HWOUT;
        int s = pos - b * HWOUT;
        float bsv = (float)bs[pos];
        size_t obase = (size_t)b * (OCH * HWOUT) + s;
        #pragma unroll
        for (int mt = 0; mt < 2; ++mt) {
            #pragma unroll
            for (int rg = 0; rg < 4; ++rg) {
                #pragma unroll
                for (int j = 0; j < 4; ++j) {
                    int o = osub + mt * 32 + rg * 8 + j + 4 * khalf;
                    float4 sc = scales[o];
                    float v = (float)acc[mt][f][rg * 4 + j];
                    out[obase + (size_t)o * HWOUT] =
                        fmaf(sc.x, v, fmaf(-sc.z, bsv, sc.y));
                }
            }
        }
    }
}

// ---------------------------------------------------------------------------
extern "C" void kernel_launch(void* const* d_in, const int* in_sizes, int n_in,
                              void* d_out, int out_size, void* d_ws, size_t ws_size,
                              hipStream_t stream)
{
    const float* x  = (const float*)d_in[0];
    const float* wt = (const float*)d_in[1];
    float* out = (float*)d_out;

    // Workspace (~29 MB), no overlaps:
    //   xq     [0,          27557888)   = NPIX*256
    //   wq     [27557888,   28147712)   = 9*256*256
    //   scales [28147712,   28151808)   = 256*16
    //   ps     [28151808,   28582400)   = NPIX*4
    //   bs     [28582400,   28983808)   = NPOS*4
    char* ws = (char*)d_ws;
    uint8_t* xq     = (uint8_t*)ws;
    uint8_t* wq     = (uint8_t*)(ws + 27557888);
    float4*  scales = (float4*)(ws + 28147712);
    int*     ps     = (int*)(ws + 28151808);
    int*     bs     = (int*)(ws + 28582400);

    // 1) x -> i8 channel-last + pixel sums (107,648 px -> 421 blocks)
    pack_xi8_kernel<<<dim3(421), dim3(256), 0, stream>>>(x, xq, ps);

    // 2) weights -> i8 [tap][o][c] + scale triples
    pack_w_kernel<<<dim3(OCH), dim3(256), 0, stream>>>(wt, wq, scales);

    // 3) 3x3 box-sum of pixel sums (100,352 -> 392 blocks)
    boxsum_kernel<<<dim3(392), dim3(256), 0, stream>>>(ps, bs);

    // 4) main MFMA conv: 392 pos-blocks x 2 o-blocks, 4 waves each
    xnor_mfma_kernel<<<dim3(392, 2), dim3(256), 0, stream>>>(xq, wq, scales, bs, out);
}